// Round 17
// baseline (205.392 us; speedup 1.0000x reference)
//
#include <hip/hip_runtime.h>

// B=2, S=32, C=256, L=640, H=5, D=128.  M = B*S*C = 16384, L = 640 = H*D.
// r16 composition + attn v3: q/k/v stored PACKED in MFMA frag order by the
// qkv epilogue; attn stages only K in LDS (80KB total -> 2 blocks/CU) and
// reads q/V frags register-direct (coalesced lane*16B, r10-validated).
//
// ws layout (bytes):
//   XB   @ 0    : x bf16 [16384][640] (written only when input is fp32)
//                 -- reused as attn_out (AT, rowmajor) after attn
//   QPK  @ SZ   : q packed [320 bsh][16 rt][4 kc][64 lane][8]  (64KB/bsh)
//   KPK  @ 2SZ  : k packed [320 bsh][16 et][4 kc][64 lane][8]
//   VPK  @ 3SZ  : v^T packed [320 bsh][8 dt][8 cc][64 lane][8]
//   WSTK @ 4SZ  : Wq|Wk|Wv stacked bf16 [1920][640]
//   WPB         : Wp bf16 [640][640];  BPB: bp bf16 [640];  FLAG: u32

typedef unsigned short u16;
typedef __bf16 bf16x8 __attribute__((ext_vector_type(8)));
typedef float f32x4 __attribute__((ext_vector_type(4)));

__device__ __forceinline__ u16 f2bf(float f){
  union { float f; unsigned u; } v; v.f = f;
  unsigned r = v.u + 0x7fffu + ((v.u >> 16) & 1u);
  return (u16)(r >> 16);
}
__device__ __forceinline__ float bf2f(u16 u){
  union { unsigned u; float f; } v; v.u = ((unsigned)u) << 16;
  return v.f;
}

__device__ __forceinline__ void gload16(const u16* g, char* l){
  __builtin_amdgcn_global_load_lds((const __attribute__((address_space(1))) void*)g,
                                   (__attribute__((address_space(3))) void*)l, 16, 0, 0);
}

// per-wave P tile [16 c][64 e], rows 128B (verified r9-r16)
__device__ __forceinline__ int p_off2(int c, int el){ return c*128 + (((el>>3) ^ (c&7)))*16 + (el&7)*2; }

// ------------------------------------------------------------------
// Fused dtype-detect + convert (r7/r16 verbatim): skip x copy when bf16.
__global__ __launch_bounds__(256) void k_convert_all(
    const void* __restrict__ xsrc, const void* __restrict__ s1, const void* __restrict__ s2,
    const void* __restrict__ s3, const void* __restrict__ s4, const void* __restrict__ s5,
    u16* __restrict__ xb, u16* __restrict__ wstk, u16* __restrict__ wpb,
    u16* __restrict__ bpb, unsigned* __restrict__ flagOut){
  __shared__ unsigned sflag;
  const int tid = threadIdx.x;
  const u16* xs = (const u16*)xsrc;
  if (tid < 64){
    int cnt = 0;
    for (int i = tid; i < 1024; i += 64){
      unsigned e = (xs[2*i] >> 7) & 0xffu;
      cnt += (e >= 143u) ? 1 : 0;
    }
    #pragma unroll
    for (int m = 1; m < 64; m <<= 1) cnt += __shfl_xor(cnt, m);
    if (tid == 0) sflag = (cnt > 16) ? 1u : 0u;
  }
  __syncthreads();
  const unsigned flag = sflag;
  if (blockIdx.x == 0 && tid == 0) *flagOut = flag;
  if (blockIdx.x < 2560 && flag == 0u) return;     // x stays in d_in[0]

  #pragma unroll
  for (int it = 0; it < 4; ++it){
    size_t i = (size_t)blockIdx.x*1024 + it*256 + tid;
    if (i >= 3031200) break;
    const void* src; size_t off; u16* dp;
    if (i < 2621440){ src = xsrc; off = i; dp = xb + i*4; }
    else {
      size_t j = i - 2621440;
      if (j < 307200){
        int seg = (int)(j / 102400);
        off = j - (size_t)seg*102400;
        src = (seg==0) ? s1 : (seg==1) ? s2 : s3;
        dp = wstk + j*4;
      } else if (j < 409600){
        off = j - 307200; src = s4; dp = wpb + off*4;
      } else { off = j - 409600; src = s5; dp = bpb + off*4; }
    }
    if (flag){
      float4 v = ((const float4*)src)[off];
      ushort4 o;
      o.x = f2bf(v.x); o.y = f2bf(v.y); o.z = f2bf(v.z); o.w = f2bf(v.w);
      *(ushort4*)dp = o;
    } else {
      *(ushort4*)dp = ((const ushort4*)src)[off];
    }
  }
}

// ------------------------------------------------------------------
// r3 gemm_core VERBATIM (measured 72.2us): 128x128, K=640, BK=64 dbuf.
__device__ __forceinline__ void gemm_core(const u16* __restrict__ Ag, const u16* __restrict__ Bg,
                                          char* lds, f32x4 acc[4][4]){
  const int tid = threadIdx.x;
  const int lane = tid & 63, wid = tid >> 6;
  const int g = lane >> 4, lo = lane & 15;
  const int wm = wid >> 1, wn = wid & 1;
  const f32x4 vzero = {0.f, 0.f, 0.f, 0.f};
  #pragma unroll
  for (int mt = 0; mt < 4; ++mt)
    #pragma unroll
    for (int nt = 0; nt < 4; ++nt) acc[mt][nt] = vzero;

  const int srow = lane >> 3;
  const size_t soff = (size_t)srow*640 + (size_t)(((lane & 7) ^ srow) * 8);

  #define STAGE(buf, kt) do {                                            \
    const u16* Akt_ = Ag + (kt)*64;                                      \
    const u16* Bkt_ = Bg + (kt)*64;                                      \
    _Pragma("unroll")                                                    \
    for (int cc = 0; cc < 4; ++cc){                                      \
      int c_ = wid*4 + cc;                                               \
      gload16(Akt_ + (size_t)c_*8*640 + soff, (buf) + c_*1024);          \
      gload16(Bkt_ + (size_t)c_*8*640 + soff, (buf) + 16384 + c_*1024);  \
    }                                                                    \
  } while(0)

  #define COMPUTE(buf) do {                                              \
    bf16x8 af[4][2], bfr[4][2];                                          \
    _Pragma("unroll")                                                    \
    for (int mt = 0; mt < 4; ++mt){                                      \
      int rr = wm*64 + mt*16 + lo;                                       \
      _Pragma("unroll")                                                  \
      for (int ks = 0; ks < 2; ++ks)                                     \
        af[mt][ks] = *(const bf16x8*)((buf) + rr*128 + (((ks*4+g) ^ (lo&7))*16)); \
    }                                                                    \
    _Pragma("unroll")                                                    \
    for (int nt = 0; nt < 4; ++nt){                                      \
      int rr = wn*64 + nt*16 + lo;                                       \
      _Pragma("unroll")                                                  \
      for (int ks = 0; ks < 2; ++ks)                                     \
        bfr[nt][ks] = *(const bf16x8*)((buf) + 16384 + rr*128 + (((ks*4+g) ^ (lo&7))*16)); \
    }                                                                    \
    _Pragma("unroll")                                                    \
    for (int mt = 0; mt < 4; ++mt)                                       \
      _Pragma("unroll")                                                  \
      for (int nt = 0; nt < 4; ++nt)                                     \
        _Pragma("unroll")                                                \
        for (int ks = 0; ks < 2; ++ks)                                   \
          acc[mt][nt] = __builtin_amdgcn_mfma_f32_16x16x32_bf16(af[mt][ks], bfr[nt][ks], acc[mt][nt], 0, 0, 0); \
  } while(0)

  char* buf0 = lds;
  char* buf1 = lds + 32768;

  STAGE(buf0, 0);
  __syncthreads();
  #pragma unroll 1
  for (int kt2 = 0; kt2 < 5; ++kt2){
    int kt = kt2*2;
    STAGE(buf1, kt+1);
    COMPUTE(buf0);
    __syncthreads();
    if (kt2 < 4) STAGE(buf0, kt+2);
    COMPUTE(buf1);
    __syncthreads();
  }
  #undef STAGE
  #undef COMPUTE
}

// QKV projection: r3 core; epilogue writes q/k/v in PACKED frag order.
// q/k: [bsh][rt=(m&255)>>4][kc=nn>>5][lane=(m&15)|(((nn>>3)&3)<<4)][nn&7]
// v  : [bsh][dt=nn>>4][cc=(m&255)>>5][lane=(nn&15)|(((m>>3)&3)<<4)][m&7]
__global__ __launch_bounds__(256, 2) void gemm_qkv(const u16* __restrict__ xraw,
    const u16* __restrict__ xb, const unsigned* __restrict__ flag,
    const u16* __restrict__ wstk,
    u16* __restrict__ qpk, u16* __restrict__ kpk, u16* __restrict__ vpk){
  __shared__ char smem[65536];
  const int m0 = blockIdx.x * 128;
  const int by = blockIdx.y;
  const u16* Ag = (*flag != 0u) ? xb : xraw;
  f32x4 acc[4][4];
  gemm_core(Ag + (size_t)m0*640, wstk + (size_t)by*128*640, smem, acc);
  const int tid = threadIdx.x, lane = tid & 63, wid = tid >> 6;
  const int g = lane >> 4, lo = lane & 15;
  const int wm = wid >> 1, wn = wid & 1;
  const int p = by / 5, h = by % 5;
  #pragma unroll
  for (int mt = 0; mt < 4; ++mt)
    #pragma unroll
    for (int nt = 0; nt < 4; ++nt)
      #pragma unroll
      for (int r = 0; r < 4; ++r){
        int m  = m0 + wm*64 + mt*16 + g*4 + r;       // global row (b,s,c)
        int nn = wn*64 + nt*16 + lo;                 // d within head, 0..127
        u16 val = f2bf(acc[mt][nt][r]);
        int bsh = (m >> 8)*5 + h;
        if (p <= 1){
          int rt = (m & 255) >> 4;
          int kc = nn >> 5;
          int l2 = (m & 15) | (((nn >> 3) & 3) << 4);
          size_t a = ((((size_t)bsh*16 + rt)*4 + kc) << 9) + l2*8 + (nn & 7);
          if (p == 0) qpk[a] = val; else kpk[a] = val;
        } else {
          int dt = nn >> 4;
          int e  = m & 255;
          int cc = e >> 5;
          int l2 = (nn & 15) | (((e >> 3) & 3) << 4);
          vpk[((((size_t)bsh*8 + dt)*8 + cc) << 9) + l2*8 + (e & 7)] = val;
        }
      }
}

// Output projection + bias (r3/r16 verbatim).
__global__ __launch_bounds__(256, 2) void gemm_out(const u16* __restrict__ at,
    const u16* __restrict__ wpw, const u16* __restrict__ bpw,
    void* __restrict__ out, const unsigned* __restrict__ flag){
  __shared__ char smem[65536];
  const int m0 = blockIdx.x * 128;
  const int n0 = blockIdx.y * 128;
  f32x4 acc[4][4];
  gemm_core(at + (size_t)m0*640, wpw + (size_t)n0*640, smem, acc);
  const int tid = threadIdx.x, lane = tid & 63, wid = tid >> 6;
  const int g = lane >> 4, lo = lane & 15;
  const int wm = wid >> 1, wn = wid & 1;
  const bool f32out = (*flag != 0u);
  #pragma unroll
  for (int mt = 0; mt < 4; ++mt)
    #pragma unroll
    for (int nt = 0; nt < 4; ++nt){
      int col = n0 + wn*64 + nt*16 + lo;
      float bv = bf2f(bpw[col]);
      #pragma unroll
      for (int r = 0; r < 4; ++r){
        int m = m0 + wm*64 + mt*16 + g*4 + r;
        float v = acc[mt][nt][r] + bv;
        if (f32out) ((float*)out)[(size_t)m*640 + col] = v;
        else        ((u16*)out)[(size_t)m*640 + col]   = f2bf(v);
      }
    }
}

// ------------------------------------------------------------------
// Attention v3: 512 thr / 8 waves, grid = 320, LDS 80KB -> 2 blocks/CU.
// K staged as LINEAR 64KB copy of KPK[bsh] (dense contiguous ds_reads);
// q and V frags register-direct from packed global (coalesced lane*16B).
// Body math/softmax/P-roundtrip = r9 verbatim.  Output rowmajor -> AT.
__global__ __launch_bounds__(512, 4) void attn_fwd(const u16* __restrict__ qpk,
    const u16* __restrict__ kpk, const u16* __restrict__ vpk, u16* __restrict__ ob){
  __shared__ char smem[81920];
  char* k_lds = smem;                // 64 KiB, linear copy of KPK[bsh]
  char* p_lds = smem + 65536;        // 16 KiB = 8 waves x [16][64]
  const int tid = threadIdx.x;
  const int lane = tid & 63, wid = tid >> 6;
  const int g = lane >> 4, lo = lane & 15;
  const int bsh = blockIdx.x;
  const int bs = bsh / 5, h = bsh % 5;
  const u16* ksrc = kpk + (size_t)bsh*32768 + lane*8;
  #pragma unroll
  for (int i = 0; i < 8; ++i){
    int c = wid*8 + i;
    gload16(ksrc + c*512, k_lds + c*1024);
  }
  __syncthreads();
  char* pw = p_lds + wid*2048;
  const float scale = 0.08838834764831845f;
  const f32x4 vzero = {0.f, 0.f, 0.f, 0.f};
  const u16* vbase = vpk + (size_t)bsh*32768 + lane*8;

  for (int mt2 = 0; mt2 < 2; ++mt2){
    const int crow = wid*32 + mt2*16;
    bf16x8 qf[4];
    #pragma unroll
    for (int kc = 0; kc < 4; ++kc)
      qf[kc] = *(const bf16x8*)(qpk + ((((size_t)bsh*16 + wid*2 + mt2)*4 + kc) << 9) + lane*8);

    f32x4 acc[16];
    #pragma unroll
    for (int et = 0; et < 16; ++et) acc[et] = vzero;
    #pragma unroll
    for (int et = 0; et < 16; ++et)
      #pragma unroll
      for (int kc = 0; kc < 4; ++kc){
        bf16x8 bk = *(const bf16x8*)(k_lds + ((et*4 + kc) << 10) + lane*16);
        acc[et] = __builtin_amdgcn_mfma_f32_16x16x32_bf16(qf[kc], bk, acc[et], 0, 0, 0);
      }

    float mx[4] = {-3.0e38f, -3.0e38f, -3.0e38f, -3.0e38f};
    #pragma unroll
    for (int et = 0; et < 16; ++et)
      #pragma unroll
      for (int r = 0; r < 4; ++r){
        float t = acc[et][r] * scale;
        acc[et][r] = t;
        mx[r] = fmaxf(mx[r], t);
      }
    #pragma unroll
    for (int msk = 1; msk < 16; msk <<= 1)
      #pragma unroll
      for (int r = 0; r < 4; ++r) mx[r] = fmaxf(mx[r], __shfl_xor(mx[r], msk));
    float sm[4] = {0.f, 0.f, 0.f, 0.f};
    #pragma unroll
    for (int et = 0; et < 16; ++et)
      #pragma unroll
      for (int r = 0; r < 4; ++r){
        float ex = __expf(acc[et][r] - mx[r]);
        acc[et][r] = ex;
        sm[r] += ex;
      }
    #pragma unroll
    for (int msk = 1; msk < 16; msk <<= 1)
      #pragma unroll
      for (int r = 0; r < 4; ++r) sm[r] += __shfl_xor(sm[r], msk);
    float inv[4];
    #pragma unroll
    for (int r = 0; r < 4; ++r) inv[r] = 1.0f / sm[r];

    f32x4 oacc[8];
    #pragma unroll
    for (int dt = 0; dt < 8; ++dt) oacc[dt] = vzero;

    #pragma unroll
    for (int half = 0; half < 2; ++half)
      #pragma unroll
      for (int sub = 0; sub < 2; ++sub){
        #pragma unroll
        for (int et2 = 0; et2 < 4; ++et2){
          int et = half*8 + sub*4 + et2;
          #pragma unroll
          for (int r = 0; r < 4; ++r)
            *(u16*)(pw + p_off2(g*4 + r, et2*16 + lo)) = f2bf(acc[et][r] * inv[r]);
        }
        asm volatile("s_waitcnt lgkmcnt(0)" ::: "memory");
        bf16x8 pf[2];
        #pragma unroll
        for (int kc = 0; kc < 2; ++kc) pf[kc] = *(const bf16x8*)(pw + p_off2(lo, kc*32 + g*8));
        #pragma unroll
        for (int dt = 0; dt < 8; ++dt)
          #pragma unroll
          for (int kc = 0; kc < 2; ++kc){
            int cc = half*4 + sub*2 + kc;
            bf16x8 bv = *(const bf16x8*)(vbase + ((((size_t)dt)*8 + cc) << 9));
            oacc[dt] = __builtin_amdgcn_mfma_f32_16x16x32_bf16(pf[kc], bv, oacc[dt], 0, 0, 0);
          }
        asm volatile("s_waitcnt lgkmcnt(0)" ::: "memory");
      }

    u16* orow = ob + ((size_t)bs*256 + crow)*640 + (size_t)h*128;
    #pragma unroll
    for (int dt = 0; dt < 8; ++dt)
      #pragma unroll
      for (int r = 0; r < 4; ++r)
        orow[(size_t)(g*4 + r)*640 + dt*16 + lo] = f2bf(oacc[dt][r]);
  }
}

// ------------------------------------------------------------------
extern "C" void kernel_launch(void* const* d_in, const int* in_sizes, int n_in,
                              void* d_out, int out_size, void* d_ws, size_t ws_size,
                              hipStream_t stream) {
  (void)in_sizes; (void)n_in; (void)out_size; (void)ws_size;
  char* ws = (char*)d_ws;
  const size_t SZ = (size_t)16384 * 640 * 2;     // 20,971,520 B
  u16* XB   = (u16*)(ws);
  u16* QPK  = (u16*)(ws + SZ);
  u16* KPK  = (u16*)(ws + 2*SZ);
  u16* VPK  = (u16*)(ws + 3*SZ);
  u16* AT   = XB;                                 // attn output (rowmajor) reuses XB
  u16* WSTK = (u16*)(ws + 4*SZ);                  // [1920][640]
  u16* WPB  = WSTK + 1228800;                     // [640][640]
  u16* BPB  = WPB + 409600;                       // [640]
  unsigned* FLAG = (unsigned*)(BPB + 640);

  k_convert_all<<<2961, 256, 0, stream>>>(d_in[0], d_in[1], d_in[2], d_in[3],
                                          d_in[4], d_in[5], XB, WSTK, WPB, BPB, FLAG);

  gemm_qkv<<<dim3(128, 15), 256, 0, stream>>>((const u16*)d_in[0], XB, FLAG,
                                              WSTK, QPK, KPK, VPK);
  attn_fwd<<<320, 512, 0, stream>>>(QPK, KPK, VPK, AT);
  gemm_out<<<dim3(128, 5), 256, 0, stream>>>(AT, WPB, BPB, d_out, FLAG);
}

// Round 18
// 148.324 us; speedup vs baseline: 1.3848x; 1.3848x over previous
//
#include <hip/hip_runtime.h>

// B=2, S=32, C=256, L=640, H=5, D=128.  M = B*S*C = 16384, L = 640 = H*D.
// FINAL best-of-breed: r7 convert (x-skip; Wp packed) + r3 gemm_core qkv
// (72.2us) + r9 attn (37us) + r10 register-B out-proj (~14us).
//
// ws layout (bytes):
//   XB   @ 0    : x bf16 [16384][640] (written only when input is fp32)
//                 -- reused as attn_out (AT, rowmajor) after attn
//   QB   @ SZ   : q bf16 [16384][640] (col = h*128+d)
//   KB   @ 2SZ  : k bf16 [16384][640]
//   VTB  @ 3SZ  : v transposed bf16 [320 bsh][128 d][256 e]
//   WSTK @ 4SZ  : Wq|Wk|Wv stacked bf16 [1920][640] (raw rowmajor)
//   WPPK        : Wp packed frag-order [40 nt][20 kb][64 lane][8]
//   BPB  bp bf16 [640];  FLAG u32 (1 = inputs fp32)

typedef unsigned short u16;
typedef __bf16 bf16x8 __attribute__((ext_vector_type(8)));
typedef float f32x4 __attribute__((ext_vector_type(4)));

__device__ __forceinline__ u16 f2bf(float f){
  union { float f; unsigned u; } v; v.f = f;
  unsigned r = v.u + 0x7fffu + ((v.u >> 16) & 1u);
  return (u16)(r >> 16);
}
__device__ __forceinline__ float bf2f(u16 u){
  union { unsigned u; float f; } v; v.u = ((unsigned)u) << 16;
  return v.f;
}

__device__ __forceinline__ void gload16(const u16* g, char* l){
  __builtin_amdgcn_global_load_lds((const __attribute__((address_space(1))) void*)g,
                                   (__attribute__((address_space(3))) void*)l, 16, 0, 0);
}

// ---- attention LDS swizzles (verified r1-r16) ----
__device__ __forceinline__ int k_off (int e, int d){ return e*256 + (((d>>3) ^ (e&7)))*16 + (d&7)*2; }
__device__ __forceinline__ int vt_off(int d, int e){ return d*512 + (((e>>3) ^ (d&7)))*16 + (e&7)*2; }
__device__ __forceinline__ int p_off2(int c, int el){ return c*128 + (((el>>3) ^ (c&7)))*16 + (el&7)*2; }

// ------------------------------------------------------------------
// Fused dtype-detect + convert: skip x when bf16; wq/wk/wv stacked raw;
// Wp packed into MFMA frag order (for register-direct B in out-proj).
// word4 segments: x [0,2621440) | wstk 307200 | wp-pack 102400 | bp 160.
__global__ __launch_bounds__(256) void k_convert_all(
    const void* __restrict__ xsrc, const void* __restrict__ s1, const void* __restrict__ s2,
    const void* __restrict__ s3, const void* __restrict__ s4, const void* __restrict__ s5,
    u16* __restrict__ xb, u16* __restrict__ wstk, u16* __restrict__ wppk,
    u16* __restrict__ bpb, unsigned* __restrict__ flagOut){
  __shared__ unsigned sflag;
  const int tid = threadIdx.x;
  const u16* xs = (const u16*)xsrc;
  if (tid < 64){
    int cnt = 0;
    for (int i = tid; i < 1024; i += 64){
      unsigned e = (xs[2*i] >> 7) & 0xffu;
      cnt += (e >= 143u) ? 1 : 0;
    }
    #pragma unroll
    for (int m = 1; m < 64; m <<= 1) cnt += __shfl_xor(cnt, m);
    if (tid == 0) sflag = (cnt > 16) ? 1u : 0u;
  }
  __syncthreads();
  const unsigned flag = sflag;
  if (blockIdx.x == 0 && tid == 0) *flagOut = flag;
  if (blockIdx.x < 2560 && flag == 0u) return;     // x stays in d_in[0]

  #pragma unroll
  for (int it = 0; it < 4; ++it){
    size_t i = (size_t)blockIdx.x*1024 + it*256 + tid;
    if (i >= 3031200) break;
    const void* src; size_t off; u16* dp;
    if (i < 2621440){ src = xsrc; off = i; dp = xb + i*4; }
    else {
      size_t j = i - 2621440;
      if (j < 307200){
        int seg = (int)(j / 102400);
        off = j - (size_t)seg*102400;
        src = (seg==0) ? s1 : (seg==1) ? s2 : s3;
        dp = wstk + j*4;
      } else if (j < 409600){
        // Wp frag-order repack (r10 verbatim)
        int j2 = (int)(j - 307200);
        int P = j2 * 4;
        int eo = P & 7;
        int grp = P >> 3;
        int lo = grp & 15, g = (grp >> 4) & 3;
        int t2 = grp >> 6;
        int kb = t2 % 20, nt = t2 / 20;
        int n = nt*16 + lo;
        int k = kb*32 + g*8 + eo;
        src = s4; off = (size_t)n*160 + (k >> 2); dp = wppk + (size_t)j2*4;
      } else { off = j - 409600; src = s5; dp = bpb + off*4; }
    }
    if (flag){
      float4 v = ((const float4*)src)[off];
      ushort4 o;
      o.x = f2bf(v.x); o.y = f2bf(v.y); o.z = f2bf(v.z); o.w = f2bf(v.w);
      *(ushort4*)dp = o;
    } else {
      *(ushort4*)dp = ((const ushort4*)src)[off];
    }
  }
}

// ------------------------------------------------------------------
// r3 gemm_core VERBATIM (measured 72.2-73.0us): 128x128, K=640, BK=64,
// double-buffered 2x32KB LDS, both operands global_load_lds, XOR swizzle.
__device__ __forceinline__ void gemm_core(const u16* __restrict__ Ag, const u16* __restrict__ Bg,
                                          char* lds, f32x4 acc[4][4]){
  const int tid = threadIdx.x;
  const int lane = tid & 63, wid = tid >> 6;
  const int g = lane >> 4, lo = lane & 15;
  const int wm = wid >> 1, wn = wid & 1;
  const f32x4 vzero = {0.f, 0.f, 0.f, 0.f};
  #pragma unroll
  for (int mt = 0; mt < 4; ++mt)
    #pragma unroll
    for (int nt = 0; nt < 4; ++nt) acc[mt][nt] = vzero;

  const int srow = lane >> 3;
  const size_t soff = (size_t)srow*640 + (size_t)(((lane & 7) ^ srow) * 8);

  #define STAGE(buf, kt) do {                                            \
    const u16* Akt_ = Ag + (kt)*64;                                      \
    const u16* Bkt_ = Bg + (kt)*64;                                      \
    _Pragma("unroll")                                                    \
    for (int cc = 0; cc < 4; ++cc){                                      \
      int c_ = wid*4 + cc;                                               \
      gload16(Akt_ + (size_t)c_*8*640 + soff, (buf) + c_*1024);          \
      gload16(Bkt_ + (size_t)c_*8*640 + soff, (buf) + 16384 + c_*1024);  \
    }                                                                    \
  } while(0)

  #define COMPUTE(buf) do {                                              \
    bf16x8 af[4][2], bfr[4][2];                                          \
    _Pragma("unroll")                                                    \
    for (int mt = 0; mt < 4; ++mt){                                      \
      int rr = wm*64 + mt*16 + lo;                                       \
      _Pragma("unroll")                                                  \
      for (int ks = 0; ks < 2; ++ks)                                     \
        af[mt][ks] = *(const bf16x8*)((buf) + rr*128 + (((ks*4+g) ^ (lo&7))*16)); \
    }                                                                    \
    _Pragma("unroll")                                                    \
    for (int nt = 0; nt < 4; ++nt){                                      \
      int rr = wn*64 + nt*16 + lo;                                       \
      _Pragma("unroll")                                                  \
      for (int ks = 0; ks < 2; ++ks)                                     \
        bfr[nt][ks] = *(const bf16x8*)((buf) + 16384 + rr*128 + (((ks*4+g) ^ (lo&7))*16)); \
    }                                                                    \
    _Pragma("unroll")                                                    \
    for (int mt = 0; mt < 4; ++mt)                                       \
      _Pragma("unroll")                                                  \
      for (int nt = 0; nt < 4; ++nt)                                     \
        _Pragma("unroll")                                                \
        for (int ks = 0; ks < 2; ++ks)                                   \
          acc[mt][nt] = __builtin_amdgcn_mfma_f32_16x16x32_bf16(af[mt][ks], bfr[nt][ks], acc[mt][nt], 0, 0, 0); \
  } while(0)

  char* buf0 = lds;
  char* buf1 = lds + 32768;

  STAGE(buf0, 0);
  __syncthreads();
  #pragma unroll 1
  for (int kt2 = 0; kt2 < 5; ++kt2){
    int kt = kt2*2;
    STAGE(buf1, kt+1);
    COMPUTE(buf0);
    __syncthreads();
    if (kt2 < 4) STAGE(buf0, kt+2);
    COMPUTE(buf1);
    __syncthreads();
  }
  #undef STAGE
  #undef COMPUTE
}

// QKV projection (r3/r16 verbatim): grid (128, 15); q/k rowmajor, v transposed.
__global__ __launch_bounds__(256, 2) void gemm_qkv(const u16* __restrict__ xraw,
    const u16* __restrict__ xb, const unsigned* __restrict__ flag,
    const u16* __restrict__ wstk,
    u16* __restrict__ qb, u16* __restrict__ kb, u16* __restrict__ vtb){
  __shared__ char smem[65536];
  const int m0 = blockIdx.x * 128;
  const int by = blockIdx.y;
  const u16* Ag = (*flag != 0u) ? xb : xraw;
  f32x4 acc[4][4];
  gemm_core(Ag + (size_t)m0*640, wstk + (size_t)by*128*640, smem, acc);
  const int tid = threadIdx.x, lane = tid & 63, wid = tid >> 6;
  const int g = lane >> 4, lo = lane & 15;
  const int wm = wid >> 1, wn = wid & 1;
  const int p = by / 5, h = by % 5;
  #pragma unroll
  for (int mt = 0; mt < 4; ++mt)
    #pragma unroll
    for (int nt = 0; nt < 4; ++nt)
      #pragma unroll
      for (int r = 0; r < 4; ++r){
        int m  = m0 + wm*64 + mt*16 + g*4 + r;
        int nn = wn*64 + nt*16 + lo;
        u16 val = f2bf(acc[mt][nt][r]);
        if (p == 0)      qb[(size_t)m*640 + h*128 + nn] = val;
        else if (p == 1) kb[(size_t)m*640 + h*128 + nn] = val;
        else             vtb[((size_t)(m >> 8)*5 + h)*32768 + (size_t)nn*256 + (m & 255)] = val;
      }
}

// ------------------------------------------------------------------
// Attention (r9/r10 verbatim, 37us): 512 thr / 8 waves, grid = 320.
__global__ __launch_bounds__(512, 1) void attn_fwd(const u16* __restrict__ qb,
    const u16* __restrict__ kb, const u16* __restrict__ vtb, u16* __restrict__ ob){
  __shared__ char smem[147456];
  char* k_lds  = smem;
  char* vt_lds = smem + 65536;
  char* p_lds  = smem + 131072;
  const int tid = threadIdx.x;
  const int bsh = blockIdx.x;
  const int bs = bsh / 5, h = bsh % 5;
  const u16* kbase = kb + (size_t)bs*256*640 + (size_t)h*128;
  const u16* vbase = vtb + (size_t)bsh*32768;
  #pragma unroll 4
  for (int i = 0; i < 8; ++i){
    int idx = i*512 + tid;
    int e = idx >> 4, cd = idx & 15;
    uint4 kv = *(const uint4*)(kbase + (size_t)e*640 + cd*8);
    *(uint4*)(k_lds + e*256 + ((cd ^ (e & 7)))*16) = kv;
    int d = idx >> 5, ce = idx & 31;
    uint4 vv = *(const uint4*)(vbase + d*256 + ce*8);
    *(uint4*)(vt_lds + d*512 + ((ce ^ (d & 7)))*16) = vv;
  }
  __syncthreads();
  const int lane = tid & 63, wid = tid >> 6;
  const int g = lane >> 4, lo = lane & 15;
  char* pw = p_lds + wid*2048;
  const float scale = 0.08838834764831845f;
  const f32x4 vzero = {0.f, 0.f, 0.f, 0.f};

  for (int mt = 0; mt < 2; ++mt){
    const int crow = wid*32 + mt*16;
    const u16* qr = qb + ((size_t)bs*256 + crow + lo)*640 + (size_t)h*128;
    bf16x8 qf[4];
    #pragma unroll
    for (int kc = 0; kc < 4; ++kc) qf[kc] = *(const bf16x8*)(qr + kc*32 + g*8);

    f32x4 acc[16];
    #pragma unroll
    for (int et = 0; et < 16; ++et) acc[et] = vzero;
    #pragma unroll
    for (int et = 0; et < 16; ++et)
      #pragma unroll
      for (int kc = 0; kc < 4; ++kc){
        bf16x8 bk = *(const bf16x8*)(k_lds + k_off(et*16 + lo, kc*32 + g*8));
        acc[et] = __builtin_amdgcn_mfma_f32_16x16x32_bf16(qf[kc], bk, acc[et], 0, 0, 0);
      }

    float mx[4] = {-3.0e38f, -3.0e38f, -3.0e38f, -3.0e38f};
    #pragma unroll
    for (int et = 0; et < 16; ++et)
      #pragma unroll
      for (int r = 0; r < 4; ++r){
        float t = acc[et][r] * scale;
        acc[et][r] = t;
        mx[r] = fmaxf(mx[r], t);
      }
    #pragma unroll
    for (int msk = 1; msk < 16; msk <<= 1)
      #pragma unroll
      for (int r = 0; r < 4; ++r) mx[r] = fmaxf(mx[r], __shfl_xor(mx[r], msk));
    float sm[4] = {0.f, 0.f, 0.f, 0.f};
    #pragma unroll
    for (int et = 0; et < 16; ++et)
      #pragma unroll
      for (int r = 0; r < 4; ++r){
        float ex = __expf(acc[et][r] - mx[r]);
        acc[et][r] = ex;
        sm[r] += ex;
      }
    #pragma unroll
    for (int msk = 1; msk < 16; msk <<= 1)
      #pragma unroll
      for (int r = 0; r < 4; ++r) sm[r] += __shfl_xor(sm[r], msk);
    float inv[4];
    #pragma unroll
    for (int r = 0; r < 4; ++r) inv[r] = 1.0f / sm[r];

    f32x4 oacc[8];
    #pragma unroll
    for (int dt = 0; dt < 8; ++dt) oacc[dt] = vzero;

    #pragma unroll
    for (int half = 0; half < 2; ++half)
      #pragma unroll
      for (int sub = 0; sub < 2; ++sub){
        #pragma unroll
        for (int et2 = 0; et2 < 4; ++et2){
          int et = half*8 + sub*4 + et2;
          #pragma unroll
          for (int r = 0; r < 4; ++r)
            *(u16*)(pw + p_off2(g*4 + r, et2*16 + lo)) = f2bf(acc[et][r] * inv[r]);
        }
        asm volatile("s_waitcnt lgkmcnt(0)" ::: "memory");
        bf16x8 pf[2];
        #pragma unroll
        for (int kc = 0; kc < 2; ++kc) pf[kc] = *(const bf16x8*)(pw + p_off2(lo, kc*32 + g*8));
        #pragma unroll
        for (int dt = 0; dt < 8; ++dt)
          #pragma unroll
          for (int kc = 0; kc < 2; ++kc){
            bf16x8 bv = *(const bf16x8*)(vt_lds + vt_off(dt*16 + lo, half*128 + sub*64 + kc*32 + g*8));
            oacc[dt] = __builtin_amdgcn_mfma_f32_16x16x32_bf16(pf[kc], bv, oacc[dt], 0, 0, 0);
          }
        asm volatile("s_waitcnt lgkmcnt(0)" ::: "memory");
      }

    u16* orow = ob + ((size_t)bs*256 + crow)*640 + (size_t)h*128;
    #pragma unroll
    for (int dt = 0; dt < 8; ++dt)
      #pragma unroll
      for (int r = 0; r < 4; ++r)
        orow[(size_t)(g*4 + r)*640 + dt*16 + lo] = f2bf(oacc[dt][r]);
  }
}

// ------------------------------------------------------------------
// Output projection (r10 gemm_rp<1> verbatim): 128x128 tile, BK=64 dbuf
// A-LDS + register-direct packed B, 3 blocks/CU.
__global__ __launch_bounds__(256, 3) void gemm_out(
    const u16* __restrict__ at, const u16* __restrict__ bpk,
    const u16* __restrict__ bpw, void* __restrict__ outp,
    const unsigned* __restrict__ flag){
  __shared__ char lds[32768];
  const int tid = threadIdx.x;
  const int lane = tid & 63, wid = tid >> 6;
  const int g = lane >> 4, lo = lane & 15;
  const int wm = wid >> 1, wn = wid & 1;
  const int m0 = blockIdx.x * 128;
  const int byn8 = blockIdx.y * 8;
  const u16* Ax = at + (size_t)m0*640;

  const int srow = lane >> 3;
  const size_t soff = (size_t)srow*640 + (size_t)(((lane & 7) ^ srow) * 8);

  #define STAGE(b, kt) do { _Pragma("unroll")                                 \
    for (int cc = 0; cc < 4; ++cc){                                           \
      int c_ = wid*4 + cc;                                                    \
      gload16(Ax + (size_t)(kt)*64 + (size_t)c_*8*640 + soff,                 \
              lds + (b)*16384 + c_*1024);                                     \
    } } while(0)

  bf16x8 bfr[4][2];
  #define LOADB(kt) do { _Pragma("unroll")                                    \
    for (int nt = 0; nt < 4; ++nt) _Pragma("unroll")                          \
      for (int ks = 0; ks < 2; ++ks)                                          \
        bfr[nt][ks] = *(const bf16x8*)(bpk +                                  \
          (((size_t)(byn8 + wn*4 + nt)*20 + (kt)*2 + ks) << 9) + lane*8);     \
  } while(0)

  f32x4 acc[4][4];
  const f32x4 vzero = {0.f, 0.f, 0.f, 0.f};
  #pragma unroll
  for (int mt = 0; mt < 4; ++mt)
    #pragma unroll
    for (int nt = 0; nt < 4; ++nt) acc[mt][nt] = vzero;

  #define COMPUTE(b) do { _Pragma("unroll")                                   \
    for (int ks = 0; ks < 2; ++ks){                                           \
      bf16x8 af[4];                                                           \
      _Pragma("unroll")                                                       \
      for (int mt = 0; mt < 4; ++mt)                                          \
        af[mt] = *(const bf16x8*)(lds + (b)*16384 +                           \
                   (wm*64 + mt*16 + lo)*128 + (((ks*4+g) ^ (lo&7))*16));      \
      _Pragma("unroll")                                                       \
      for (int mt = 0; mt < 4; ++mt) _Pragma("unroll")                        \
        for (int nt = 0; nt < 4; ++nt)                                        \
          acc[mt][nt] = __builtin_amdgcn_mfma_f32_16x16x32_bf16(              \
              af[mt], bfr[nt][ks], acc[mt][nt], 0, 0, 0);                     \
    } } while(0)

  STAGE(0, 0);
  __syncthreads();
  #pragma unroll 1
  for (int kt2 = 0; kt2 < 5; ++kt2){
    LOADB(2*kt2);
    STAGE(1, 2*kt2 + 1);
    COMPUTE(0);
    __syncthreads();
    LOADB(2*kt2 + 1);
    if (kt2 < 4) STAGE(0, 2*kt2 + 2);
    COMPUTE(1);
    __syncthreads();
  }
  #undef STAGE
  #undef LOADB
  #undef COMPUTE

  const bool f32out = (*flag != 0u);
  #pragma unroll
  for (int mt = 0; mt < 4; ++mt)
    #pragma unroll
    for (int nt = 0; nt < 4; ++nt)
      #pragma unroll
      for (int r = 0; r < 4; ++r){
        int m  = m0 + wm*64 + mt*16 + g*4 + r;
        int nn = wn*64 + nt*16 + lo;
        int col = blockIdx.y*128 + nn;
        float v = acc[mt][nt][r] + bf2f(bpw[col]);
        if (f32out) ((float*)outp)[(size_t)m*640 + col] = v;
        else        ((u16*)outp)[(size_t)m*640 + col]   = f2bf(v);
      }
}

// ------------------------------------------------------------------
extern "C" void kernel_launch(void* const* d_in, const int* in_sizes, int n_in,
                              void* d_out, int out_size, void* d_ws, size_t ws_size,
                              hipStream_t stream) {
  (void)in_sizes; (void)n_in; (void)out_size; (void)ws_size;
  char* ws = (char*)d_ws;
  const size_t SZ = (size_t)16384 * 640 * 2;     // 20,971,520 B
  u16* XB   = (u16*)(ws);
  u16* QB   = (u16*)(ws + SZ);
  u16* KB   = (u16*)(ws + 2*SZ);
  u16* VTB  = (u16*)(ws + 3*SZ);
  u16* AT   = XB;                                 // attn output reuses XB
  u16* WSTK = (u16*)(ws + 4*SZ);                  // [1920][640] raw
  u16* WPPK = WSTK + 1228800;                     // packed Wp: 409,600 u16
  u16* BPB  = WPPK + 409600;                      // [640]
  unsigned* FLAG = (unsigned*)(BPB + 640);

  k_convert_all<<<2961, 256, 0, stream>>>(d_in[0], d_in[1], d_in[2], d_in[3],
                                          d_in[4], d_in[5], XB, WSTK, WPPK, BPB, FLAG);

  gemm_qkv<<<dim3(128, 15), 256, 0, stream>>>((const u16*)d_in[0], XB, FLAG,
                                              WSTK, QB, KB, VTB);
  attn_fwd<<<320, 512, 0, stream>>>(QB, KB, VTB, AT);
  gemm_out<<<dim3(128, 5), 256, 0, stream>>>(AT, WPPK, BPB, d_out, FLAG);
}